// Round 7
// baseline (10020.757 us; speedup 1.0000x reference)
//
#include <hip/hip_runtime.h>
#include <hip/hip_bf16.h>

#define DEV __device__ __forceinline__

typedef __bf16 bf16;
typedef __bf16 bf16x8 __attribute__((ext_vector_type(8)));
typedef float f32x4 __attribute__((ext_vector_type(4)));
typedef int i32x4 __attribute__((ext_vector_type(4)));
typedef unsigned int u32;
typedef unsigned long long u64;

// problem constants
#define BB 32
#define TT 512
#define DIN 1024
#define HH 512
#define G4 2048          // 4H
#define MM (TT*BB)       // 16384 rows (t-major: r = t*32 + b)
#define TAGMAGIC 0x5A000000u

DEV float sigmf(float x){ return 1.0f/(1.0f + __expf(-x)); }
DEV float tanhfast(float x){ return 1.0f - 2.0f/(__expf(2.0f*x)+1.0f); }

DEV void gload16(const void* g, void* l){
  __builtin_amdgcn_global_load_lds((const __attribute__((address_space(1))) void*)g,
                                   (__attribute__((address_space(3))) void*)l, 16, 0, 0);
}

// coherence-point (bypass L1+L2) accessors — cross-XCD visible without cache flushes
DEV i32x4 cload16(const void* p){
  i32x4 v;
  asm volatile("global_load_dwordx4 %0, %1, off sc0 sc1"
               : "=&v"(v) : "v"(p) : "memory");
  return v;
}
DEV void cstore16(void* p, i32x4 v){
  asm volatile("global_store_dwordx4 %0, %1, off sc0 sc1"
               :: "v"(p), "v"(v) : "memory");
}
DEV void waitvm0(){ asm volatile("s_waitcnt vmcnt(0)" ::: "memory"); }

// ---------------- debug: report ws_size via absmax ----------------
__global__ void k_dbg(float* out, float v){ out[0] = v; }

// ---------------- prep: bias sum ----------------
__global__ void k_prep_bias(const float* __restrict__ bx, const float* __restrict__ bh,
                            float* __restrict__ bsum){
  int gid = blockIdx.x*256 + threadIdx.x;
  if (gid < 4*G4) bsum[gid] = bx[gid] + bh[gid];
}

// ---------------- x -> bf16, row r = t*32+b, XOR-swizzled 16B chunks ----------------
__global__ void k_xswz(const float* __restrict__ x, bf16* __restrict__ xs){
  int gid = blockIdx.x*256 + threadIdx.x;   // 16384*128
  int r = gid >> 7, kc = gid & 127;
  int b = r & 31, t = r >> 5;
  const float* px = x + ((size_t)b*TT + t)*DIN + kc*8;
  float4 v0 = *(const float4*)px;
  float4 v1 = *(const float4*)(px+4);
  bf16x8 o;
  o[0]=(bf16)v0.x; o[1]=(bf16)v0.y; o[2]=(bf16)v0.z; o[3]=(bf16)v0.w;
  o[4]=(bf16)v1.x; o[5]=(bf16)v1.y; o[6]=(bf16)v1.z; o[7]=(bf16)v1.w;
  *(bf16x8*)(xs + (size_t)r*DIN + ((kc ^ (r&7))<<3)) = o;
}

// ---------------- Wx: [ld][k=1024][n=2048] f32 -> [ld][n][k] bf16, swizzled ----------------
__global__ void k_twx(const float* __restrict__ Wx, bf16* __restrict__ Wxt){
  int ld = blockIdx.z;
  int k0 = blockIdx.x*64, n0 = blockIdx.y*64;
  const float* in = Wx + (size_t)ld*DIN*G4;
  bf16* outp = Wxt + (size_t)ld*G4*DIN;
  __shared__ float tile[64][68];
  int tid = threadIdx.x;
  #pragma unroll
  for (int rr=0; rr<4; rr++){
    int row = rr*16 + (tid>>4); int c4 = (tid&15)*4;
    float4 v = *(const float4*)(in + (size_t)(k0+row)*G4 + n0 + c4);
    *(float4*)&tile[row][c4] = v;
  }
  __syncthreads();
  #pragma unroll
  for (int uu=0; uu<2; uu++){
    int u = uu*256 + tid;
    int nn = u>>3, ck = u&7;
    bf16x8 o;
    #pragma unroll
    for (int j=0;j<8;j++) o[j] = (bf16)tile[ck*8+j][nn];
    int ncol = n0 + nn;
    int kcg = (k0>>3) + ck;
    *(bf16x8*)(outp + (size_t)ncol*DIN + ((size_t)(kcg ^ (ncol&7))<<3)) = o;
  }
}

// ---------------- Wh: [ld][k=512][n=2048] f32 -> [ld][cc][k] bf16 (col remap) ----------------
__global__ void k_twh(const float* __restrict__ Wh, bf16* __restrict__ Whb){
  int ld = blockIdx.z;
  int k0 = blockIdx.x*64, n0 = blockIdx.y*64;
  const float* in = Wh + (size_t)ld*HH*G4;
  bf16* outp = Whb + (size_t)ld*G4*HH;
  __shared__ float tile[64][68];
  int tid = threadIdx.x;
  #pragma unroll
  for (int rr=0; rr<4; rr++){
    int row = rr*16 + (tid>>4); int c4 = (tid&15)*4;
    float4 v = *(const float4*)(in + (size_t)(k0+row)*G4 + n0 + c4);
    *(float4*)&tile[row][c4] = v;
  }
  __syncthreads();
  #pragma unroll
  for (int uu=0; uu<2; uu++){
    int u = uu*256 + tid;
    int nn = u>>3, ck = u&7;
    bf16x8 o;
    #pragma unroll
    for (int j=0;j<8;j++) o[j] = (bf16)tile[ck*8+j][nn];
    int n = n0 + nn;
    int q = n >> 9, rem = n & 511;
    int s = rem >> 4, wq = (rem >> 2) & 3, hcv = rem & 3;
    int cc = s*64 + wq*16 + q*4 + hcv;   // gate-interleaved col order
    *(bf16x8*)(outp + (size_t)cc*HH + k0 + ck*8) = o;
  }
}

// ---------------- gx GEMM: [16384,1024]bf16 @ [1024,2048]bf16 -> GXT (+bias) ----------------
template<typename GXT>
__launch_bounds__(256, 1)
__global__ void k_gemm(const bf16* __restrict__ A, const bf16* __restrict__ Bw,
                       const float* __restrict__ bias, GXT* __restrict__ out){
  int d = blockIdx.z;
  const bf16* Bp = Bw + (size_t)d*G4*DIN;
  const float* bp = bias + d*G4;
  GXT* op = out + (size_t)d*MM*G4;
  int n0 = blockIdx.x*128, r0 = blockIdx.y*128;
  int tid = threadIdx.x, lane = tid&63, w = tid>>6;
  __shared__ __align__(16) bf16 ldsA[128*64];
  __shared__ __align__(16) bf16 ldsB[128*64];
  f32x4 acc[4][4];
  #pragma unroll
  for (int i=0;i<4;i++)
    #pragma unroll
    for (int j=0;j<4;j++) acc[i][j] = (f32x4){0.f,0.f,0.f,0.f};
  int wm = w>>1, wn = w&1;
  for (int kt=0; kt<16; kt++){
    __syncthreads();
    #pragma unroll
    for (int p=0;p<4;p++){
      int seg = p*4 + w;
      int row = seg*8 + (lane>>3);
      int cch = lane&7;
      gload16(A  + (size_t)(r0+row)*DIN + kt*64 + cch*8, ldsA + seg*512);
      gload16(Bp + (size_t)(n0+row)*DIN + kt*64 + cch*8, ldsB + seg*512);
    }
    __syncthreads();
    #pragma unroll
    for (int ks=0; ks<2; ks++){
      bf16x8 af[4], bf_[4];
      #pragma unroll
      for (int at=0; at<4; at++){
        int row = wm*64 + at*16 + (lane&15);
        int ch = (ks*4 + (lane>>4)) ^ (row&7);
        af[at] = *(const bf16x8*)(ldsA + row*64 + ch*8);
      }
      #pragma unroll
      for (int bt=0; bt<4; bt++){
        int col = wn*64 + bt*16 + (lane&15);
        int ch = (ks*4 + (lane>>4)) ^ (col&7);
        bf_[bt] = *(const bf16x8*)(ldsB + col*64 + ch*8);
      }
      #pragma unroll
      for (int at=0; at<4; at++)
        #pragma unroll
        for (int bt=0; bt<4; bt++)
          acc[at][bt] = __builtin_amdgcn_mfma_f32_16x16x32_bf16(af[at], bf_[bt], acc[at][bt], 0,0,0);
    }
  }
  float bv[4];
  #pragma unroll
  for (int bt=0;bt<4;bt++) bv[bt] = bp[n0 + wn*64 + bt*16 + (lane&15)];
  #pragma unroll
  for (int at=0; at<4; at++)
    #pragma unroll
    for (int bt=0; bt<4; bt++)
      #pragma unroll
      for (int rg=0; rg<4; rg++){
        int row = r0 + wm*64 + at*16 + (lane>>4)*4 + rg;
        int col = n0 + wn*64 + bt*16 + (lane&15);
        op[(size_t)row*G4 + col] = (GXT)(acc[at][bt][rg] + bv[bt]);
      }
}

// ---------------- fused recurrence: 32 WGs, BOTH directions per WG ----------------
// SMT-across-directions: per step, phase d=0 then d=1. Each phase's
// publish->visibility latency is hidden under the OTHER direction's compute.
// Tagged-unit protocol unchanged: 16B = {4xbf16 | u32 tag | pad}, sc0sc1.
template<typename GXT>
__launch_bounds__(256, 1)
__global__ void k_rec2(const bf16* __restrict__ Whb, const GXT* __restrict__ gx,
                       char* __restrict__ hbT,
                       bf16* __restrict__ out0, float* __restrict__ dout,
                       float* __restrict__ hn, float* __restrict__ cn, int layer){
  int tid = threadIdx.x, lane = tid&63, w = tid>>6;
  int s = blockIdx.x;                         // 0..31 col-slice
  __shared__ __align__(16) bf16 hA[32*512];   // 32KB, XOR-swizzled, shared by phases
  __shared__ __align__(8) unsigned short hP[4*128]; // per-wave publish pack
  bf16x8 bfr[2][16];                          // both dirs' Wh slices in regs (128 VGPR)
  #pragma unroll
  for (int d=0; d<2; d++){
    const bf16* Wp = Whb + ((size_t)d*G4 + s*64 + w*16 + (lane&15))*HH;
    #pragma unroll
    for (int kk=0; kk<16; kk++) bfr[d][kk] = *(const bf16x8*)(Wp + kk*32 + (lane>>4)*8);
  }
  float cst[2][2][4] = {};
  int q = (lane>>2)&3, hc = lane&3;
  int colg = q*HH + s*16 + w*4 + hc;
  int m0 = lane&15;
  bool hi = (q >= 2), odd = (q & 1);
  u32 tagb0 = TAGMAGIC + (u32)((layer*2+0)*TT);
  u32 tagb1 = TAGMAGIC + (u32)((layer*2+1)*TT);

  for (int t=0; t<TT; t++){
    // gx prefetch for BOTH dirs, issued before any staging (hidden under polls)
    GXT gxr[2][2][4];
    #pragma unroll
    for (int d=0; d<2; d++){
      int tt = d ? (TT-1-t) : t;
      const GXT* gp = gx + (size_t)d*MM*G4 + (size_t)tt*BB*G4 + colg;
      #pragma unroll
      for (int mt=0; mt<2; mt++)
        #pragma unroll
        for (int rg=0; rg<4; rg++)
          gxr[d][mt][rg] = gp[(size_t)(mt*16 + (lane>>4)*4 + rg)*G4];
    }
    #pragma unroll
    for (int d=0; d<2; d++){
      int tt = d ? (TT-1-t) : t;
      u32 tagbase = d ? tagb1 : tagb0;
      f32x4 acc0 = {0.f,0.f,0.f,0.f}, acc1 = {0.f,0.f,0.f,0.f};
      if (t > 0){
        // ---- tagged staging: load h_{t-1} of dir d (slot (t-1)&1), poll-by-tag ----
        const char* sT = hbT + ((size_t)(d*2 + ((t-1)&1)) << 16);  // 4096 units * 16B
        u32 want = tagbase + (u32)t;   // tag of h_{t-1}
        i32x4 u[16];
        #pragma unroll
        for (int i=0;i<16;i++){ int g = i*256 + tid; u[i] = cload16(sT + ((size_t)g<<4)); }
        waitvm0();
        __builtin_amdgcn_sched_barrier(0);
        while (true){
          bool bad = false;
          #pragma unroll
          for (int i=0;i<16;i++) bad |= ((u32)u[i].z != want);
          if (!__any(bad)) break;
          __builtin_amdgcn_s_sleep(1);
          #pragma unroll
          for (int i=0;i<16;i++) if ((u32)u[i].z != want){ int g = i*256 + tid; u[i] = cload16(sT + ((size_t)g<<4)); }
          waitvm0();
          __builtin_amdgcn_sched_barrier(0);
        }
        __syncthreads();   // all waves done with previous phase's hA MFMA
        #pragma unroll
        for (int i=0;i<16;i++){
          int g = i*256 + tid; int b = g>>7, cu = g&127;
          u64 dat = ((u64)(u32)u[i].y << 32) | (u32)u[i].x;
          *(u64*)((char*)hA + b*1024 + ((((cu>>1) ^ (b&7)))<<4) + (cu&1)*8) = dat;
        }
        __syncthreads();   // hA ready
        #pragma unroll
        for (int kk=0; kk<16; kk++){
          int ch = (kk*4 + (lane>>4)) ^ (m0&7);
          bf16x8 a0 = *(const bf16x8*)(hA + m0*HH + ch*8);
          bf16x8 a1 = *(const bf16x8*)(hA + (m0+16)*HH + ch*8);
          acc0 = __builtin_amdgcn_mfma_f32_16x16x32_bf16(a0, bfr[d][kk], acc0, 0,0,0);
          acc1 = __builtin_amdgcn_mfma_f32_16x16x32_bf16(a1, bfr[d][kk], acc1, 0,0,0);
        }
      }
      // gates + cell update (gate exchange inside 16-lane groups via shfl_xor)
      #pragma unroll
      for (int mt=0; mt<2; mt++){
        #pragma unroll
        for (int rg=0; rg<4; rg++){
          float gpre = (mt ? acc1[rg] : acc0[rg]) + (float)gxr[d][mt][rg];
          float x4  = __shfl_xor(gpre, 4);
          float x8  = __shfl_xor(gpre, 8);
          float x12 = __shfl_xor(gpre, 12);
          float a04 = odd ? x4 : gpre,  b04 = odd ? gpre : x4;
          float a812 = odd ? x12 : x8,  b812 = odd ? x8 : x12;
          float ig = hi ? a812 : a04;
          float fg = hi ? b812 : b04;
          float gg = hi ? a04 : a812;
          float og = hi ? b04 : b812;
          float iv = sigmf(ig), fv = sigmf(fg), gv = tanhfast(gg), ov = sigmf(og);
          float c = cst[d][mt][rg]*fv + iv*gv;
          cst[d][mt][rg] = c;
          float hvv = ov * tanhfast(c);
          if (q == 0){
            int b = mt*16 + (lane>>4)*4 + rg;
            hP[w*128 + b*4 + hc] = __builtin_bit_cast(unsigned short, (bf16)hvv);
            if (layer == 1)
              __builtin_nontemporal_store(hvv,
                dout + ((size_t)(b*TT + tt))*(2*HH) + d*HH + s*16 + w*4 + hc);
            if (t == TT-1)
              hn[((size_t)((layer*2+d)*BB + b))*HH + s*16 + w*4 + hc] = hvv;
          }
        }
      }
      if (t == TT-1 && q == 0){
        #pragma unroll
        for (int mt=0; mt<2; mt++)
          #pragma unroll
          for (int rg=0; rg<4; rg++){
            int b = mt*16 + (lane>>4)*4 + rg;
            cn[((size_t)((layer*2+d)*BB + b))*HH + s*16 + w*4 + hc] = cst[d][mt][rg];
          }
      }
      // ---- per-wave publish: pack via tiny LDS, fire-and-forget tagged stores ----
      if (lane < 32){
        u64 d8 = *(const u64*)(hP + w*128 + lane*4);   // row=lane, 4 cols
        if (t < TT-1){
          char* dT = hbT + ((size_t)(d*2 + (t&1)) << 16);
          i32x4 unit;
          unit.x = (int)(u32)(d8 & 0xffffffffu);
          unit.y = (int)(u32)(d8 >> 32);
          unit.z = (int)(tagbase + (u32)t + 1u);
          unit.w = 0;
          cstore16(dT + ((size_t)(lane*128 + s*4 + w) << 4), unit);
        }
        if (layer == 0){
          int r = tt*BB + lane;
          int c = d*64 + s*2 + (w>>1);
          *(u64*)(out0 + (size_t)r*DIN + (size_t)(c ^ (r&7))*8 + (w&1)*4) = d8;
        }
      }
    }
  }
}

extern "C" void kernel_launch(void* const* d_in, const int* in_sizes, int n_in,
                              void* d_out, int out_size, void* d_ws, size_t ws_size,
                              hipStream_t stream){
  const float* x  = (const float*)d_in[0];
  const float* Wx = (const float*)d_in[1];
  const float* bx = (const float*)d_in[2];
  const float* Wh = (const float*)d_in[3];
  const float* bh = (const float*)d_in[4];
  float* outp = (float*)d_out;
  char* ws = (char*)d_ws;

  const size_t szWxt  = (size_t)4*G4*DIN*2;   // 16.8 MB
  const size_t szWhb  = (size_t)4*G4*HH*2;    // 8.4 MB
  const size_t szBsum = (size_t)4*G4*4;
  const size_t szXO   = (size_t)MM*DIN*2;     // 33.6 MB
  const size_t szHbT  = (size_t)2*2*4096*16;  // 256 KB tagged h buffers

  // mode 0: f32 gx (~327 MB) | mode 1: bf16 gx (~193 MB); xo/out0 shared
  int mode = -1;
  size_t oWxt=0,oWhb=0,oBsum=0,oXO=0,oHbT=0,oGx=0;
  for (int m=0; m<2 && mode<0; m++){
    size_t off = 0;
    auto take = [&](size_t b)->size_t{ size_t r = off; off = (off + b + 255) & ~(size_t)255; return r; };
    oWxt = take(szWxt); oWhb = take(szWhb); oBsum = take(szBsum);
    oXO  = take(szXO);
    oHbT = take(szHbT);
    size_t gxb = (m==0) ? (size_t)2*MM*G4*4 : (size_t)2*MM*G4*2;
    oGx = take(gxb);
    if (off <= ws_size) mode = m;
  }
  if (mode < 0){
    k_dbg<<<1, 1, 0, stream>>>(outp, (float)((double)ws_size / 1048576.0));
    return;
  }

  bf16* Wxt  = (bf16*)(ws + oWxt);
  bf16* Whb  = (bf16*)(ws + oWhb);
  float* bsum= (float*)(ws + oBsum);
  bf16* xo   = (bf16*)(ws + oXO);
  bf16* out0 = xo;                       // layer-0 h overwrites x-image (safe: GEMM done)
  char* hbT  = ws + oHbT;
  void* gxp  = (void*)(ws + oGx);

  float* hn = outp + (size_t)BB*TT*2*HH;
  float* cn = hn + (size_t)4*BB*HH;

  hipMemsetAsync(hbT, 0, szHbT, stream);   // clean tags every launch (graph-safe)
  k_prep_bias<<<32, 256, 0, stream>>>(bx, bh, bsum);
  k_xswz<<<(MM*128)/256, 256, 0, stream>>>(x, xo);
  k_twx<<<dim3(16,32,4), 256, 0, stream>>>(Wx, Wxt);
  k_twh<<<dim3(8,32,4), 256, 0, stream>>>(Wh, Whb);

  if (mode == 0){
    float* gx = (float*)gxp;
    for (int layer=0; layer<2; layer++){
      k_gemm<float><<<dim3(16,128,2), 256, 0, stream>>>(xo, Wxt + (size_t)layer*2*G4*DIN,
                                                        bsum + layer*2*G4, gx);
      k_rec2<float><<<32, 256, 0, stream>>>(Whb + (size_t)layer*2*G4*HH, gx, hbT,
                                            out0, outp, hn, cn, layer);
    }
  } else {
    bf16* gx = (bf16*)gxp;
    for (int layer=0; layer<2; layer++){
      k_gemm<bf16><<<dim3(16,128,2), 256, 0, stream>>>(xo, Wxt + (size_t)layer*2*G4*DIN,
                                                       bsum + layer*2*G4, gx);
      k_rec2<bf16><<<32, 256, 0, stream>>>(Whb + (size_t)layer*2*G4*HH, gx, hbT,
                                           out0, outp, hn, cn, layer);
    }
  }
}

// Round 8
// 5766.215 us; speedup vs baseline: 1.7378x; 1.7378x over previous
//
#include <hip/hip_runtime.h>
#include <hip/hip_bf16.h>

#define DEV __device__ __forceinline__

typedef __bf16 bf16;
typedef __bf16 bf16x8 __attribute__((ext_vector_type(8)));
typedef float f32x4 __attribute__((ext_vector_type(4)));
typedef int i32x4 __attribute__((ext_vector_type(4)));
typedef unsigned int u32;
typedef unsigned long long u64;

// problem constants
#define BB 32
#define TT 512
#define DIN 1024
#define HH 512
#define G4 2048          // 4H
#define MM (TT*BB)       // 16384 rows (t-major: r = t*32 + b)
#define TAGMAGIC 0x5A000000u

DEV float sigmf(float x){ return 1.0f/(1.0f + __expf(-x)); }
DEV float tanhfast(float x){ return 1.0f - 2.0f/(__expf(2.0f*x)+1.0f); }

DEV void gload16(const void* g, void* l){
  __builtin_amdgcn_global_load_lds((const __attribute__((address_space(1))) void*)g,
                                   (__attribute__((address_space(3))) void*)l, 16, 0, 0);
}

// coherence-point (bypass L1+L2) accessors — cross-XCD visible without cache flushes
DEV i32x4 cload16(const void* p){
  i32x4 v;
  asm volatile("global_load_dwordx4 %0, %1, off sc0 sc1"
               : "=&v"(v) : "v"(p) : "memory");
  return v;
}
DEV void cstore16(void* p, i32x4 v){
  asm volatile("global_store_dwordx4 %0, %1, off sc0 sc1"
               :: "v"(p), "v"(v) : "memory");
}
DEV void waitvm0(){ asm volatile("s_waitcnt vmcnt(0)" ::: "memory"); }

// ---------------- debug: report ws_size via absmax ----------------
__global__ void k_dbg(float* out, float v){ out[0] = v; }

// ---------------- prep: bias sum ----------------
__global__ void k_prep_bias(const float* __restrict__ bx, const float* __restrict__ bh,
                            float* __restrict__ bsum){
  int gid = blockIdx.x*256 + threadIdx.x;
  if (gid < 4*G4) bsum[gid] = bx[gid] + bh[gid];
}

// ---------------- x -> bf16, row r = t*32+b, XOR-swizzled 16B chunks ----------------
__global__ void k_xswz(const float* __restrict__ x, bf16* __restrict__ xs){
  int gid = blockIdx.x*256 + threadIdx.x;   // 16384*128
  int r = gid >> 7, kc = gid & 127;
  int b = r & 31, t = r >> 5;
  const float* px = x + ((size_t)b*TT + t)*DIN + kc*8;
  float4 v0 = *(const float4*)px;
  float4 v1 = *(const float4*)(px+4);
  bf16x8 o;
  o[0]=(bf16)v0.x; o[1]=(bf16)v0.y; o[2]=(bf16)v0.z; o[3]=(bf16)v0.w;
  o[4]=(bf16)v1.x; o[5]=(bf16)v1.y; o[6]=(bf16)v1.z; o[7]=(bf16)v1.w;
  *(bf16x8*)(xs + (size_t)r*DIN + ((kc ^ (r&7))<<3)) = o;
}

// ---------------- Wx: [ld][k=1024][n=2048] f32 -> [ld][n][k] bf16, swizzled ----------------
__global__ void k_twx(const float* __restrict__ Wx, bf16* __restrict__ Wxt){
  int ld = blockIdx.z;
  int k0 = blockIdx.x*64, n0 = blockIdx.y*64;
  const float* in = Wx + (size_t)ld*DIN*G4;
  bf16* outp = Wxt + (size_t)ld*G4*DIN;
  __shared__ float tile[64][68];
  int tid = threadIdx.x;
  #pragma unroll
  for (int rr=0; rr<4; rr++){
    int row = rr*16 + (tid>>4); int c4 = (tid&15)*4;
    float4 v = *(const float4*)(in + (size_t)(k0+row)*G4 + n0 + c4);
    *(float4*)&tile[row][c4] = v;
  }
  __syncthreads();
  #pragma unroll
  for (int uu=0; uu<2; uu++){
    int u = uu*256 + tid;
    int nn = u>>3, ck = u&7;
    bf16x8 o;
    #pragma unroll
    for (int j=0;j<8;j++) o[j] = (bf16)tile[ck*8+j][nn];
    int ncol = n0 + nn;
    int kcg = (k0>>3) + ck;
    *(bf16x8*)(outp + (size_t)ncol*DIN + ((size_t)(kcg ^ (ncol&7))<<3)) = o;
  }
}

// ---------------- Wh: [ld][k=512][n=2048] f32 -> [ld][cc][k] bf16 (col remap) ----------------
__global__ void k_twh(const float* __restrict__ Wh, bf16* __restrict__ Whb){
  int ld = blockIdx.z;
  int k0 = blockIdx.x*64, n0 = blockIdx.y*64;
  const float* in = Wh + (size_t)ld*HH*G4;
  bf16* outp = Whb + (size_t)ld*G4*HH;
  __shared__ float tile[64][68];
  int tid = threadIdx.x;
  #pragma unroll
  for (int rr=0; rr<4; rr++){
    int row = rr*16 + (tid>>4); int c4 = (tid&15)*4;
    float4 v = *(const float4*)(in + (size_t)(k0+row)*G4 + n0 + c4);
    *(float4*)&tile[row][c4] = v;
  }
  __syncthreads();
  #pragma unroll
  for (int uu=0; uu<2; uu++){
    int u = uu*256 + tid;
    int nn = u>>3, ck = u&7;
    bf16x8 o;
    #pragma unroll
    for (int j=0;j<8;j++) o[j] = (bf16)tile[ck*8+j][nn];
    int n = n0 + nn;
    int q = n >> 9, rem = n & 511;
    int s = rem >> 4, wq = (rem >> 2) & 3, hcv = rem & 3;
    int cc = s*64 + wq*16 + q*4 + hcv;   // gate-interleaved col order
    *(bf16x8*)(outp + (size_t)cc*HH + k0 + ck*8) = o;
  }
}

// ---------------- gx GEMM -> PERMUTED bf16 layout (+bias) ----------------
// Output unit (16B = bf16x8) at ((tt*32 + s)*256 + tid_rec)*8 holds exactly the
// 8 gate-preacts rec-thread tid_rec of slice s needs at step tt (j = mt*4+rg).
// Each GEMM lane owns whole units: j=(at&1)*4+rg come from acc[2a..2a+1][bt].
__launch_bounds__(256, 1)
__global__ void k_gemmp(const bf16* __restrict__ A, const bf16* __restrict__ Bw,
                        const float* __restrict__ bias, bf16* __restrict__ out){
  int d = blockIdx.z;
  const bf16* Bp = Bw + (size_t)d*G4*DIN;
  const float* bp = bias + d*G4;
  bf16* op = out + (size_t)d*MM*G4;
  int n0 = blockIdx.x*128, r0 = blockIdx.y*128;
  int tid = threadIdx.x, lane = tid&63, w = tid>>6;
  __shared__ __align__(16) bf16 ldsA[128*64];
  __shared__ __align__(16) bf16 ldsB[128*64];
  f32x4 acc[4][4];
  #pragma unroll
  for (int i=0;i<4;i++)
    #pragma unroll
    for (int j=0;j<4;j++) acc[i][j] = (f32x4){0.f,0.f,0.f,0.f};
  int wm = w>>1, wn = w&1;
  for (int kt=0; kt<16; kt++){
    __syncthreads();
    #pragma unroll
    for (int p=0;p<4;p++){
      int seg = p*4 + w;
      int row = seg*8 + (lane>>3);
      int cch = lane&7;
      gload16(A  + (size_t)(r0+row)*DIN + kt*64 + cch*8, ldsA + seg*512);
      gload16(Bp + (size_t)(n0+row)*DIN + kt*64 + cch*8, ldsB + seg*512);
    }
    __syncthreads();
    #pragma unroll
    for (int ks=0; ks<2; ks++){
      bf16x8 af[4], bf_[4];
      #pragma unroll
      for (int at=0; at<4; at++){
        int row = wm*64 + at*16 + (lane&15);
        int ch = (ks*4 + (lane>>4)) ^ (row&7);
        af[at] = *(const bf16x8*)(ldsA + row*64 + ch*8);
      }
      #pragma unroll
      for (int bt=0; bt<4; bt++){
        int col = wn*64 + bt*16 + (lane&15);
        int ch = (ks*4 + (lane>>4)) ^ (col&7);
        bf_[bt] = *(const bf16x8*)(ldsB + col*64 + ch*8);
      }
      #pragma unroll
      for (int at=0; at<4; at++)
        #pragma unroll
        for (int bt=0; bt<4; bt++)
          acc[at][bt] = __builtin_amdgcn_mfma_f32_16x16x32_bf16(af[at], bf_[bt], acc[at][bt], 0,0,0);
    }
  }
  float bv[4];
  #pragma unroll
  for (int bt=0;bt<4;bt++) bv[bt] = bp[n0 + wn*64 + bt*16 + (lane&15)];
  int l4 = lane>>4;
  #pragma unroll
  for (int a=0; a<2; a++){
    int tt = (r0 + wm*64 + a*32) >> 5;
    #pragma unroll
    for (int bt=0; bt<4; bt++){
      int col = n0 + wn*64 + bt*16 + (lane&15);
      int q = col >> 9, rem = col & 511;
      int sD = rem >> 4, wR = (rem >> 2) & 3, hcD = rem & 3;
      int tIdx = wR*64 + l4*16 + q*4 + hcD;
      bf16x8 u8;
      #pragma unroll
      for (int j=0;j<4;j++) u8[j]   = (bf16)(acc[a*2][bt][j]   + bv[bt]);
      #pragma unroll
      for (int j=0;j<4;j++) u8[4+j] = (bf16)(acc[a*2+1][bt][j] + bv[bt]);
      *(bf16x8*)(op + (((size_t)tt*32 + sD)*256 + tIdx)*8) = u8;
    }
  }
}

// ---------------- recurrence: 64 WGs = 2 dirs x 32 col-slices ----------------
// Tagged-unit protocol (16B = {4xbf16 | u32 tag | pad}, sc0sc1 fire-and-forget).
// gx read = ONE coalesced 16B bf16x8 per thread per step (permuted layout).
__launch_bounds__(256, 1)
__global__ void k_rec(const bf16* __restrict__ Whb, const bf16* __restrict__ gx,
                      char* __restrict__ hbT,
                      bf16* __restrict__ out0, float* __restrict__ dout,
                      float* __restrict__ hn, float* __restrict__ cn, int layer){
  int tid = threadIdx.x, lane = tid&63, w = tid>>6;
  int d = blockIdx.x >> 5, s = blockIdx.x & 31;
  __shared__ __align__(16) bf16 hA[32*512];   // 32KB, XOR-swizzled
  __shared__ __align__(8) unsigned short hP[4*128]; // per-wave publish pack
  const bf16* Wp = Whb + ((size_t)d*G4 + s*64 + w*16 + (lane&15))*HH;
  bf16x8 bfr[16];
  #pragma unroll
  for (int kk=0; kk<16; kk++) bfr[kk] = *(const bf16x8*)(Wp + kk*32 + (lane>>4)*8);
  float cst[2][4] = {{0,0,0,0},{0,0,0,0}};
  const bf16* gxD = gx + (size_t)d*MM*G4;
  const u32 tagbase = TAGMAGIC + (u32)((layer*2 + d)*TT);
  int q = (lane>>2)&3, hc = lane&3;
  int m0 = lane&15;
  bool hi = (q >= 2), odd = (q & 1);

  for (int t=0; t<TT; t++){
    int tt = d ? (TT-1-t) : t;
    // gx: ONE coalesced 16B load, issued before staging (hidden under poll RT)
    bf16x8 gv = *(const bf16x8*)(gxD + (((size_t)tt*32 + s)*256 + tid)*8);
    f32x4 acc0 = {0.f,0.f,0.f,0.f}, acc1 = {0.f,0.f,0.f,0.f};
    if (t > 0){
      // ---- tagged staging: load h_{t-1} (slot (t-1)&1), poll-by-tag ----
      const char* sT = hbT + ((size_t)(d*2 + ((t-1)&1)) << 16);  // 4096 units * 16B
      u32 want = tagbase + (u32)t;   // tag of h_{t-1}
      i32x4 u[16];
      #pragma unroll
      for (int i=0;i<16;i++){ int g = i*256 + tid; u[i] = cload16(sT + ((size_t)g<<4)); }
      waitvm0();
      __builtin_amdgcn_sched_barrier(0);
      while (true){
        bool bad = false;
        #pragma unroll
        for (int i=0;i<16;i++) bad |= ((u32)u[i].z != want);
        if (!__any(bad)) break;
        __builtin_amdgcn_s_sleep(1);
        #pragma unroll
        for (int i=0;i<16;i++) if ((u32)u[i].z != want){ int g = i*256 + tid; u[i] = cload16(sT + ((size_t)g<<4)); }
        waitvm0();
        __builtin_amdgcn_sched_barrier(0);
      }
      __syncthreads();   // all waves' MFMA of t-1 done -> hA may be overwritten
      #pragma unroll
      for (int i=0;i<16;i++){
        int g = i*256 + tid; int b = g>>7, cu = g&127;
        u64 dat = ((u64)(u32)u[i].y << 32) | (u32)u[i].x;
        *(u64*)((char*)hA + b*1024 + ((((cu>>1) ^ (b&7)))<<4) + (cu&1)*8) = dat;
      }
      __syncthreads();   // hA ready
      #pragma unroll
      for (int kk=0; kk<16; kk++){
        int ch = (kk*4 + (lane>>4)) ^ (m0&7);
        bf16x8 a0 = *(const bf16x8*)(hA + m0*HH + ch*8);
        bf16x8 a1 = *(const bf16x8*)(hA + (m0+16)*HH + ch*8);
        acc0 = __builtin_amdgcn_mfma_f32_16x16x32_bf16(a0, bfr[kk], acc0, 0,0,0);
        acc1 = __builtin_amdgcn_mfma_f32_16x16x32_bf16(a1, bfr[kk], acc1, 0,0,0);
      }
    }
    // gates + cell update (gate exchange inside 16-lane groups via shfl_xor)
    #pragma unroll
    for (int mt=0; mt<2; mt++){
      #pragma unroll
      for (int rg=0; rg<4; rg++){
        float gpre = (mt ? acc1[rg] : acc0[rg]) + (float)gv[mt*4+rg];
        float x4  = __shfl_xor(gpre, 4);
        float x8  = __shfl_xor(gpre, 8);
        float x12 = __shfl_xor(gpre, 12);
        float a04 = odd ? x4 : gpre,  b04 = odd ? gpre : x4;
        float a812 = odd ? x12 : x8,  b812 = odd ? x8 : x12;
        float ig = hi ? a812 : a04;
        float fg = hi ? b812 : b04;
        float gg = hi ? a04 : a812;
        float og = hi ? b04 : b812;
        float iv = sigmf(ig), fv = sigmf(fg), gv_ = tanhfast(gg), ov = sigmf(og);
        float c = cst[mt][rg]*fv + iv*gv_;
        cst[mt][rg] = c;
        float hvv = ov * tanhfast(c);
        if (q == 0){
          int b = mt*16 + (lane>>4)*4 + rg;
          hP[w*128 + b*4 + hc] = __builtin_bit_cast(unsigned short, (bf16)hvv);
          if (layer == 1)
            __builtin_nontemporal_store(hvv,
              dout + ((size_t)(b*TT + tt))*(2*HH) + d*HH + s*16 + w*4 + hc);
          if (t == TT-1)
            hn[((size_t)((layer*2+d)*BB + b))*HH + s*16 + w*4 + hc] = hvv;
        }
      }
    }
    if (t == TT-1 && q == 0){
      #pragma unroll
      for (int mt=0; mt<2; mt++)
        #pragma unroll
        for (int rg=0; rg<4; rg++){
          int b = mt*16 + (lane>>4)*4 + rg;
          cn[((size_t)((layer*2+d)*BB + b))*HH + s*16 + w*4 + hc] = cst[mt][rg];
        }
    }
    // ---- per-wave publish: pack via tiny LDS, fire-and-forget tagged stores ----
    if (lane < 32){
      u64 d8 = *(const u64*)(hP + w*128 + lane*4);   // row=lane, 4 cols
      if (t < TT-1){
        char* dT = hbT + ((size_t)(d*2 + (t&1)) << 16);
        i32x4 unit;
        unit.x = (int)(u32)(d8 & 0xffffffffu);
        unit.y = (int)(u32)(d8 >> 32);
        unit.z = (int)(tagbase + (u32)t + 1u);
        unit.w = 0;
        cstore16(dT + ((size_t)(lane*128 + s*4 + w) << 4), unit);
      }
      if (layer == 0){
        int r = tt*BB + lane;
        int c = d*64 + s*2 + (w>>1);
        *(u64*)(out0 + (size_t)r*DIN + (size_t)(c ^ (r&7))*8 + (w&1)*4) = d8;
      }
    }
  }
}

extern "C" void kernel_launch(void* const* d_in, const int* in_sizes, int n_in,
                              void* d_out, int out_size, void* d_ws, size_t ws_size,
                              hipStream_t stream){
  const float* x  = (const float*)d_in[0];
  const float* Wx = (const float*)d_in[1];
  const float* bx = (const float*)d_in[2];
  const float* Wh = (const float*)d_in[3];
  const float* bh = (const float*)d_in[4];
  float* outp = (float*)d_out;
  char* ws = (char*)d_ws;

  const size_t szWxt  = (size_t)4*G4*DIN*2;   // 16.8 MB
  const size_t szWhb  = (size_t)4*G4*HH*2;    // 8.4 MB
  const size_t szBsum = (size_t)4*G4*4;
  const size_t szXO   = (size_t)MM*DIN*2;     // 33.6 MB
  const size_t szHbT  = (size_t)2*2*4096*16;  // 256 KB tagged h buffers
  const size_t szGx   = (size_t)2*MM*G4*2;    // 134 MB bf16 permuted gx

  size_t off = 0;
  auto take = [&](size_t b)->size_t{ size_t r = off; off = (off + b + 255) & ~(size_t)255; return r; };
  size_t oWxt = take(szWxt), oWhb = take(szWhb), oBsum = take(szBsum);
  size_t oXO  = take(szXO), oHbT = take(szHbT), oGx = take(szGx);
  if (off > ws_size){
    k_dbg<<<1, 1, 0, stream>>>(outp, (float)((double)ws_size / 1048576.0));
    return;
  }

  bf16* Wxt  = (bf16*)(ws + oWxt);
  bf16* Whb  = (bf16*)(ws + oWhb);
  float* bsum= (float*)(ws + oBsum);
  bf16* xo   = (bf16*)(ws + oXO);
  bf16* out0 = xo;                 // layer-0 h overwrites x-image (GEMM reads done)
  char* hbT  = ws + oHbT;
  bf16* gx   = (bf16*)(ws + oGx);

  float* hn = outp + (size_t)BB*TT*2*HH;
  float* cn = hn + (size_t)4*BB*HH;

  hipMemsetAsync(hbT, 0, szHbT, stream);   // clean tags every launch (graph-safe)
  k_prep_bias<<<32, 256, 0, stream>>>(bx, bh, bsum);
  k_xswz<<<(MM*128)/256, 256, 0, stream>>>(x, xo);
  k_twx<<<dim3(16,32,4), 256, 0, stream>>>(Wx, Wxt);
  k_twh<<<dim3(8,32,4), 256, 0, stream>>>(Wh, Whb);

  for (int layer=0; layer<2; layer++){
    k_gemmp<<<dim3(16,128,2), 256, 0, stream>>>(xo, Wxt + (size_t)layer*2*G4*DIN,
                                                bsum + layer*2*G4, gx);
    k_rec<<<64, 256, 0, stream>>>(Whb + (size_t)layer*2*G4*HH, gx, hbT,
                                  out0, outp, hn, cn, layer);
  }
}